// Round 17
// baseline (663.823 us; speedup 1.0000x reference)
//
#include <hip/hip_runtime.h>
#include <math.h>

#define NBANDS 31
#define FT 257000

typedef __attribute__((ext_vector_type(8))) short bh8;
typedef __attribute__((ext_vector_type(4))) float f4;
typedef __attribute__((ext_vector_type(4))) float f4v;

__constant__ int d_bs[NBANDS] = {0,1,1,2,2,2,3,3,4,5,6,7,8,10,11,13,16,19,23,27,32,38,45,54,64,76,91,108,128,152,181};
__constant__ int d_be[NBANDS] = {2,3,3,3,4,4,5,6,7,8,9,11,12,14,17,20,24,28,33,39,46,55,65,77,92,109,129,153,182,216,257};

__device__ __forceinline__ unsigned short b16u(float v) {
  __bf16 h = (__bf16)v;
  return __builtin_bit_cast(unsigned short, h);
}
__device__ __forceinline__ unsigned pk2(float a, float b) {
  return (unsigned)b16u(a) | ((unsigned)b16u(b) << 16);
}
__device__ __forceinline__ float hann1(int i, int L) {
  return 0.5f - 0.5f * cosf(6.283185307179586f * (float)i / (float)L);
}

// ---- weight f32 -> bf16 prep, permuted into MFMA-fragment order (enc + qkvo) ----
__global__ __launch_bounds__(256) void prep_w(
    const float* __restrict__ enc_w, const float* __restrict__ dec_w,
    const float* __restrict__ qw, const float* __restrict__ kw,
    const float* __restrict__ vw, const float* __restrict__ ow,
    unsigned short* __restrict__ w16) {
  const int stride = gridDim.x * blockDim.x;
  for (int i = blockIdx.x * blockDim.x + threadIdx.x; i < 513024; i += stride) {
    float v;
    if (i < 190464) {                      // enc: K=64, KT=2
      const int k = i / 6144, r = i - k * 6144;
      const int tile = r >> 9, li = r & 511;
      const int lane = li >> 3, j = li & 7;
      const int g = lane >> 4, n = lane & 15;
      const int mt = tile >> 1, kt = tile & 1;
      v = enc_w[k * 6144 + (mt * 16 + n) * 64 + kt * 32 + g * 8 + j];
    } else if (i < 476160) {               // legacy dec slot (unused by fused paths)
      const int i2 = i - 190464;
      const int k = i2 / 9216, r = i2 - k * 9216;
      const int tile = r >> 9, li = r & 511;
      const int lane = li >> 3, j = li & 7;
      const int g = lane >> 4, n = lane & 15;
      const int mt = tile / 3, kt = tile - mt * 3;
      v = dec_w[k * 9216 + (mt * 16 + n) * 96 + kt * 32 + g * 8 + j];
    } else {                               // q,k,v,o
      const int i2 = i - 476160;
      const int a = i2 / 9216, r = i2 - a * 9216;
      const int tile = r >> 9, li = r & 511;
      const int lane = li >> 3, j = li & 7;
      const int g = lane >> 4, n = lane & 15;
      const int mt = tile / 3, kt = tile - mt * 3;
      const float* src = (a == 0) ? qw : (a == 1) ? kw : (a == 2) ? vw : ow;
      v = src[(mt * 16 + n) * 96 + kt * 32 + g * 8 + j];
    }
    w16[i] = b16u(v);
  }
}

__global__ __launch_bounds__(192) void qp_kernel(const float* __restrict__ doa,
                                                 const float* __restrict__ dqg_w,
                                                 const float* __restrict__ dqg_b,
                                                 float* __restrict__ gbuf) {
  const int k = blockIdx.x, b = blockIdx.y;
  const int tid = threadIdx.x;
  __shared__ float sdoa[36];
  if (tid < 36) sdoa[tid] = doa[b * 36 + tid];
  __syncthreads();
  const float* wr = dqg_w + (k * 192 + tid) * 36;
  float acc = dqg_b[k * 192 + tid];
  #pragma unroll
  for (int i = 0; i < 36; ++i) acc = fmaf(wr[i], sdoa[i], acc);
  if (tid < 96) acc += 1.0f;
  gbuf[(k * 4 + b) * 192 + tid] = acc;
}

// ---- FiLM fold ----
__global__ __launch_bounds__(96) void prep_dec(
    const float* __restrict__ dec_w, const float* __restrict__ dec_b,
    const float* __restrict__ gbuf,
    unsigned short* __restrict__ dec16b, float* __restrict__ decBb) {
  const int k = blockIdx.x, b = blockIdx.y;
  const int o = threadIdx.x;
  __shared__ float gm[96], bt[96];
  gm[o] = gbuf[(k * 4 + b) * 192 + o];
  bt[o] = gbuf[(k * 4 + b) * 192 + 96 + o];
  __syncthreads();
  const float* wr = dec_w + k * 9216 + o * 96;
  float bias = dec_b[k * 96 + o];
  unsigned short* dst = dec16b + (b * 31 + k) * 9216;
  const int mt = o >> 4, n = o & 15;
  for (int c = 0; c < 96; ++c) {
    const float wv = wr[c];
    bias = fmaf(wv, bt[c], bias);
    const int kt = c >> 5, g = (c & 31) >> 3, j = c & 7;
    dst[((mt * 3 + kt) << 9) + (((g << 4) + n) << 3) + j] = b16u(wv * gm[c]);
  }
  decBb[(b * 31 + k) * 96 + o] = bias;
}

// ---- per-f table ----
__global__ __launch_bounds__(320) void tab_kernel(float* __restrict__ ftab) {
  const int f = blockIdx.x * blockDim.x + threadIdx.x;
  if (f >= 257) return;
  int k0 = 0; while (d_be[k0] <= f) ++k0;
  int k1 = k0; while (k1 < NBANDS && d_bs[k1] <= f) ++k1;
  float wsum = 0.f, wn[5];
  for (int k = k0; k < k1; ++k) {
    const float wv = hann1(f - d_bs[k], d_be[k] - d_bs[k]);
    wn[k - k0] = wv; wsum += wv;
  }
  float* o = ftab + f * 8;
  o[0] = (float)k0; o[1] = (float)(k1 - k0); o[2] = 1.0f / fmaxf(wsum, 1e-8f);
  #pragma unroll
  for (int j = 0; j < 5; ++j) o[3 + j] = (j < k1 - k0) ? wn[j] : 0.f;
}

#define LDSWAIT asm volatile("s_waitcnt lgkmcnt(0)" ::: "memory")
#define PRIO1 __builtin_amdgcn_s_setprio(1)
#define PRIO0 __builtin_amdgcn_s_setprio(0)

__device__ __forceinline__ void init6(f4* acc, const float* s, int off) {
  #pragma unroll
  for (int mt = 0; mt < 6; ++mt) {
    const float4 bb = *reinterpret_cast<const float4*>(s + mt * 16 + off);
    acc[mt] = (f4){bb.x, bb.y, bb.z, bb.w};
  }
}
__device__ __forceinline__ f4 init1(const float* s, int mt, int off) {
  const float4 bb = *reinterpret_cast<const float4*>(s + mt * 16 + off);
  return (f4){bb.x, bb.y, bb.z, bb.w};
}
__device__ __forceinline__ void ln96(const f4* acc, float& mean, float& rs) {
  float s0 = 0.f, s1 = 0.f, s2 = 0.f, s3 = 0.f;
  float q0 = 0.f, q1 = 0.f, q2 = 0.f, q3 = 0.f;
  #pragma unroll
  for (int mt = 0; mt < 6; ++mt) {
    const float a0 = acc[mt][0], a1 = acc[mt][1], a2 = acc[mt][2], a3 = acc[mt][3];
    s0 += a0; s1 += a1; s2 += a2; s3 += a3;
    q0 = fmaf(a0, a0, q0); q1 = fmaf(a1, a1, q1);
    q2 = fmaf(a2, a2, q2); q3 = fmaf(a3, a3, q3);
  }
  float sm = (s0 + s1) + (s2 + s3);
  float sq = (q0 + q1) + (q2 + q3);
  sm += __shfl_xor(sm, 16); sm += __shfl_xor(sm, 32);
  sq += __shfl_xor(sq, 16); sq += __shfl_xor(sq, 32);
  mean = sm * (1.f / 96.f);
  rs = rsqrtf(sq * (1.f / 96.f) - mean * mean + 1e-5f);
}
__device__ __forceinline__ void load6s(bh8* dst, const unsigned short* p, int step9) {
  #pragma unroll
  for (int mt = 0; mt < 6; ++mt)
    dst[mt] = *reinterpret_cast<const bh8*>(p + ((mt * step9) << 9));
}

// ================= PHASE 1: band loop -> merged B-fragments (gfr) =================
__global__ __launch_bounds__(256, 4) void band_mfma(
    const float* __restrict__ spin,
    const unsigned short* __restrict__ enc16, const float* __restrict__ enc_b, const float* __restrict__ enc_a,
    const unsigned short* __restrict__ dec16b, const float* __restrict__ decBb, const float* __restrict__ dec_a,
    const float* __restrict__ ftab,
    bh8* __restrict__ gout) {
  const int id0 = (int)blockIdx.x;
  const int id  = (id0 & 7) * 2056 + (id0 >> 3);
  const int tt  = id & 15;
  const int fb  = id >> 4;
  const int f   = fb % 257;
  const int b   = fb / 257;
  const int t0  = tt << 6;

  const int tid  = threadIdx.x;
  const int lane = tid & 63;
  const int w    = tid >> 6;
  const int g    = lane >> 4;
  const int n    = lane & 15;
  const int col  = (w << 4) + n;
  const int t    = t0 + col;
  const int tcl  = (t < 1000) ? t : 999;
  const int sw   = (n & 7) << 3;
  const int lb   = lane << 3;
  const int bk   = b * 31;

  __shared__ __align__(16) unsigned short XT[64 * 128];
  __shared__ __align__(16) float stage[5 * 256];
  unsigned short* xw = XT + col * 128;

  const float* ft = ftab + f * 8;
  const int k0 = (int)ft[0];
  const int nb = (int)ft[1];
  const float winv = ft[2];

  {
    const int tot = nb << 8;
    for (int i = tid; i < tot; i += 256) {
      const int kk = i >> 8, r = i & 255;
      const int k = k0 + kk;
      float v = 0.f;
      if      (r < 96)  v = enc_b[k * 96 + r];
      else if (r < 192) v = decBb[(bk + k) * 96 + (r - 96)];
      else if (r == 192) v = enc_a[k];
      else if (r == 193) v = dec_a[k];
      else if (r == 194) v = ft[3 + kk];
      stage[i] = v;
    }
  }

  const float* spL = spin + b * 64 * FT + f * 1000 + tcl;

  bh8 spb[2];
  {
    float spf[16];
    #pragma unroll
    for (int j = 0; j < 8; ++j) spf[j]     = __builtin_nontemporal_load(spL + (g * 8 + j) * FT);
    #pragma unroll
    for (int j = 0; j < 8; ++j) spf[8 + j] = __builtin_nontemporal_load(spL + (32 + g * 8 + j) * FT);
    #pragma unroll
    for (int kt = 0; kt < 2; ++kt)
      #pragma unroll
      for (int j = 0; j < 8; ++j) spb[kt][j] = (short)b16u(spf[kt * 8 + j]);
  }

  bh8 pre[6];
  load6s(pre, enc16 + k0 * 6144 + lb, 2);

  __syncthreads();

  f4 macc[6];
  #pragma unroll
  for (int mt = 0; mt < 6; ++mt) macc[mt] = (f4){0.f, 0.f, 0.f, 0.f};

  const int oo = g * 4;

  for (int kk = 0; kk < nb; ++kk) {
    const int k = k0 + kk;
    const unsigned short* ew  = enc16 + k * 6144 + lb;
    const unsigned short* dwp = dec16b + (bk + k) * 9216 + lb;
    const float* stg = stage + (kk << 8);

    f4 acc[6];
    init6(acc, stg, oo);
    PRIO1;
    #pragma unroll
    for (int mt = 0; mt < 6; ++mt)
      acc[mt] = __builtin_amdgcn_mfma_f32_16x16x32_bf16(pre[mt], spb[0], acc[mt], 0, 0, 0);
    #pragma unroll
    for (int mt = 0; mt < 6; ++mt) {
      const bh8 af = *reinterpret_cast<const bh8*>(ew + ((mt * 2 + 1) << 9));
      acc[mt] = __builtin_amdgcn_mfma_f32_16x16x32_bf16(af, spb[1], acc[mt], 0, 0, 0);
    }
    PRIO0;

    load6s(pre, dwp, 3);

    float mean, rs;
    ln96(acc, mean, rs);
    const float ea = stg[192];
    #pragma unroll
    for (int mt = 0; mt < 6; ++mt) {
      float x0 = (acc[mt][0] - mean) * rs; x0 = (x0 >= 0.f) ? x0 : ea * x0;
      float x1 = (acc[mt][1] - mean) * rs; x1 = (x1 >= 0.f) ? x1 : ea * x1;
      float x2 = (acc[mt][2] - mean) * rs; x2 = (x2 >= 0.f) ? x2 : ea * x2;
      float x3 = (acc[mt][3] - mean) * rs; x3 = (x3 >= 0.f) ? x3 : ea * x3;
      uint2 u;
      u.x = pk2(x0, x1);
      u.y = pk2(x2, x3);
      *reinterpret_cast<uint2*>(xw + ((mt * 16 + oo) ^ sw)) = u;
    }
    LDSWAIT;

    f4 dacc[6];
    init6(dacc, stg + 96, oo);
    PRIO1;
    {
      const bh8 bf0 = *reinterpret_cast<const bh8*>(xw + ((0 * 32 + g * 8) ^ sw));
      #pragma unroll
      for (int mt = 0; mt < 6; ++mt)
        dacc[mt] = __builtin_amdgcn_mfma_f32_16x16x32_bf16(pre[mt], bf0, dacc[mt], 0, 0, 0);
    }
    PRIO0;

    {
      const bool more = (kk + 1 < nb);
      if (more) load6s(pre, enc16 + (k + 1) * 6144 + lb, 2);
    }

    PRIO1;
    #pragma unroll
    for (int kt = 1; kt < 3; ++kt) {
      const bh8 bf = *reinterpret_cast<const bh8*>(xw + ((kt * 32 + g * 8) ^ sw));
      #pragma unroll
      for (int mt = 0; mt < 6; ++mt) {
        const bh8 af = *reinterpret_cast<const bh8*>(dwp + ((mt * 3 + kt) << 9));
        dacc[mt] = __builtin_amdgcn_mfma_f32_16x16x32_bf16(af, bf, dacc[mt], 0, 0, 0);
      }
    }
    PRIO0;
    float mean2, rs2;
    ln96(dacc, mean2, rs2);
    const float da = stg[193];
    const float win = stg[194];
    #pragma unroll
    for (int mt = 0; mt < 6; ++mt)
      #pragma unroll
      for (int r = 0; r < 4; ++r) {
        float x = (dacc[mt][r] - mean2) * rs2;
        x = (x >= 0.f) ? x : da * x;
        macc[mt][r] = fmaf(win, x, macc[mt][r]);
      }
  }

  // merged -> XT -> B-fragments -> global (coalesced, cached/full-line)
  #pragma unroll
  for (int mt = 0; mt < 6; ++mt) {
    uint2 u;
    u.x = pk2(macc[mt][0] * winv, macc[mt][1] * winv);
    u.y = pk2(macc[mt][2] * winv, macc[mt][3] * winv);
    *reinterpret_cast<uint2*>(xw + ((mt * 16 + oo) ^ sw)) = u;
  }
  LDSWAIT;
  bh8* gw = gout + (long)id * 768 + w * 192 + lane;
  #pragma unroll
  for (int kt = 0; kt < 3; ++kt) {
    const bh8 gfr = *reinterpret_cast<const bh8*>(xw + ((kt * 32 + g * 8) ^ sw));
    gw[kt * 64] = gfr;
  }
}

// ================= PHASE 2: QKVO from merged fragments =================
__global__ __launch_bounds__(256, 5) void qkvo_mfma(
    const float* __restrict__ mix, const bh8* __restrict__ gin,
    const unsigned short* __restrict__ q16, const float* __restrict__ qb,
    const unsigned short* __restrict__ k16, const float* __restrict__ kb,
    const unsigned short* __restrict__ v16, const float* __restrict__ vb,
    const unsigned short* __restrict__ o16, const float* __restrict__ ob,
    float* __restrict__ out) {
  const int id0 = (int)blockIdx.x;
  const int id  = (id0 & 7) * 2056 + (id0 >> 3);
  const int tt  = id & 15;
  const int fb  = id >> 4;
  const int f   = fb % 257;
  const int b   = fb / 257;
  const int t0  = tt << 6;

  const int tid  = threadIdx.x;
  const int lane = tid & 63;
  const int w    = tid >> 6;
  const int g    = lane >> 4;
  const int n    = lane & 15;
  const int col  = (w << 4) + n;
  const int t    = t0 + col;
  const int tcl  = (t < 1000) ? t : 999;
  const int sw   = (n & 7) << 3;
  const int lb   = lane << 3;

  // LDS: XT[16384] + stage floats @26112 (1536B); OS[26112] aliases from 0
  __shared__ __align__(16) char smem[27648];
  unsigned short* XT = (unsigned short*)smem;
  float* stage = (float*)(smem + 26112);
  float* OS = (float*)smem;
  unsigned short* xw = XT + col * 128;

  // stage qb|kb|vb|ob
  for (int i = tid; i < 384; i += 256) {
    float v = (i < 96) ? qb[i] : (i < 192) ? kb[i - 96] : (i < 288) ? vb[i - 192] : ob[i - 288];
    stage[i] = v;
  }

  const float* mxL = mix + b * 96 * FT + f * 1000 + tcl;

  // merged fragments (coalesced, L3-resident)
  bh8 gfr[3];
  {
    const bh8* gr = gin + (long)id * 768 + w * 192 + lane;
    #pragma unroll
    for (int kt = 0; kt < 3; ++kt) gfr[kt] = gr[kt * 64];
  }

  // mix fragments
  bh8 mxb[3];
  {
    float mxf[24];
    #pragma unroll
    for (int kt = 0; kt < 3; ++kt)
      #pragma unroll
      for (int j = 0; j < 8; ++j) mxf[kt * 8 + j] = mxL[(kt * 32 + g * 8 + j) * FT];
    #pragma unroll
    for (int kt = 0; kt < 3; ++kt)
      #pragma unroll
      for (int j = 0; j < 8; ++j) mxb[kt][j] = (short)b16u(mxf[kt * 8 + j]);
  }

  __syncthreads();   // stage visible

  const int oo = g * 4;
  const unsigned short* qp16 = q16 + lb;
  const unsigned short* kp16 = k16 + lb;
  const unsigned short* vp16 = v16 + lb;
  const unsigned short* op16 = o16 + lb;

  // Q,K per-mt
  float p0 = 0.f, p1 = 0.f;
  #pragma unroll
  for (int mt = 0; mt < 6; ++mt) {
    f4 qa = init1(stage, mt, oo);
    f4 ka = init1(stage + 96, mt, oo);
    PRIO1;
    #pragma unroll
    for (int kt = 0; kt < 3; ++kt) {
      const bh8 af = *reinterpret_cast<const bh8*>(qp16 + ((mt * 3 + kt) << 9));
      qa = __builtin_amdgcn_mfma_f32_16x16x32_bf16(af, mxb[kt], qa, 0, 0, 0);
    }
    #pragma unroll
    for (int kt = 0; kt < 3; ++kt) {
      const bh8 af = *reinterpret_cast<const bh8*>(kp16 + ((mt * 3 + kt) << 9));
      ka = __builtin_amdgcn_mfma_f32_16x16x32_bf16(af, gfr[kt], ka, 0, 0, 0);
    }
    PRIO0;
    p0 = fmaf(qa[0], ka[0], p0);
    p1 = fmaf(qa[1], ka[1], p1);
    p0 = fmaf(qa[2], ka[2], p0);
    p1 = fmaf(qa[3], ka[3], p1);
  }
  float p = p0 + p1;
  p += __shfl_xor(p, 16); p += __shfl_xor(p, 32);
  const float sig = 1.f / (1.f + __expf(-p * 0.10206207261596575f));

  // V per-mt -> XT
  #pragma unroll
  for (int mt = 0; mt < 6; ++mt) {
    f4 va = init1(stage + 192, mt, oo);
    PRIO1;
    #pragma unroll
    for (int kt = 0; kt < 3; ++kt) {
      const bh8 af = *reinterpret_cast<const bh8*>(vp16 + ((mt * 3 + kt) << 9));
      va = __builtin_amdgcn_mfma_f32_16x16x32_bf16(af, gfr[kt], va, 0, 0, 0);
    }
    PRIO0;
    uint2 u;
    u.x = pk2(va[0] * sig, va[1] * sig);
    u.y = pk2(va[2] * sig, va[3] * sig);
    *reinterpret_cast<uint2*>(xw + ((mt * 16 + oo) ^ sw)) = u;
  }
  LDSWAIT;
  bh8 afr[3];
  #pragma unroll
  for (int kt = 0; kt < 3; ++kt) afr[kt] = *reinterpret_cast<const bh8*>(xw + ((kt * 32 + g * 8) ^ sw));

  // O per-mt
  f4 oacc[6];
  init6(oacc, stage + 288, oo);
  PRIO1;
  #pragma unroll
  for (int kt = 0; kt < 3; ++kt)
    #pragma unroll
    for (int mt = 0; mt < 6; ++mt) {
      const bh8 af = *reinterpret_cast<const bh8*>(op16 + ((mt * 3 + kt) << 9));
      oacc[mt] = __builtin_amdgcn_mfma_f32_16x16x32_bf16(af, afr[kt], oacc[mt], 0, 0, 0);
    }
  PRIO0;

  __syncthreads();   // all waves done with XT/stage before aliased OS writes

  #pragma unroll
  for (int mt = 0; mt < 6; ++mt)
    #pragma unroll
    for (int r = 0; r < 4; ++r)
      OS[(mt * 16 + oo + r) * 68 + col] = oacc[mt][r];

  __syncthreads();

  // coalesced epilogue: residual add + NT store
  const int cvalid = 1000 - t0;
  if (cvalid >= 64) {
    #pragma unroll
    for (int it = 0; it < 6; ++it) {
      const int i   = it * 256 + tid;
      const int row = i >> 4;
      const int c4  = (i & 15) << 2;
      f4v v = *reinterpret_cast<const f4v*>(&OS[row * 68 + c4]);
      const long gi = (long)(b * 96 + row) * FT + f * 1000 + t0 + c4;
      const f4v m = *reinterpret_cast<const f4v*>(mix + gi);
      v = v + m;
      __builtin_nontemporal_store(v, reinterpret_cast<f4v*>(out + gi));
    }
  } else {
    #pragma unroll
    for (int it = 0; it < 24; ++it) {
      const int i   = it * 256 + tid;
      const int row = i >> 6;
      const int c   = i & 63;
      if (c < cvalid) {
        const long gi = (long)(b * 96 + row) * FT + f * 1000 + t0 + c;
        __builtin_nontemporal_store(OS[row * 68 + c] + mix[gi], out + gi);
      }
    }
  }
}

// ================= MONOLITH FALLBACK (R16) =================
__global__ __launch_bounds__(256, 3) void fused_mfma(
    const float* __restrict__ mix, const float* __restrict__ spin,
    const unsigned short* __restrict__ enc16, const float* __restrict__ enc_b, const float* __restrict__ enc_a,
    const unsigned short* __restrict__ dec16b, const float* __restrict__ decBb, const float* __restrict__ dec_a,
    const float* __restrict__ ftab,
    const unsigned short* __restrict__ q16, const float* __restrict__ qb,
    const unsigned short* __restrict__ k16, const float* __restrict__ kb,
    const unsigned short* __restrict__ v16, const float* __restrict__ vb,
    const unsigned short* __restrict__ o16, const float* __restrict__ ob,
    float* __restrict__ out) {
  const int id0 = (int)blockIdx.x;
  const int id  = (id0 & 7) * 2056 + (id0 >> 3);
  const int tt  = id & 15;
  const int fb  = id >> 4;
  const int f   = fb % 257;
  const int b   = fb / 257;
  const int t0  = tt << 6;

  const int tid  = threadIdx.x;
  const int lane = tid & 63;
  const int w    = tid >> 6;
  const int g    = lane >> 4;
  const int n    = lane & 15;
  const int col  = (w << 4) + n;
  const int t    = t0 + col;
  const int tcl  = (t < 1000) ? t : 999;
  const int sw   = (n & 7) << 3;
  const int lb   = lane << 3;
  const int bk   = b * 31;

  __shared__ __align__(16) char smem[26112];
  unsigned short* XT = (unsigned short*)smem;
  float* stage = (float*)(smem + 16384);
  float* OS = (float*)smem;
  unsigned short* xw = XT + col * 128;

  const float* ft = ftab + f * 8;
  const int k0 = (int)ft[0];
  const int nb = (int)ft[1];
  const float winv = ft[2];

  {
    const int tot = (nb << 8) + 384;
    for (int i = tid; i < tot; i += 256) {
      const int kk = i >> 8, r = i & 255;
      float v = 0.f;
      if (kk < nb) {
        const int k = k0 + kk;
        if      (r < 96)  v = enc_b[k * 96 + r];
        else if (r < 192) v = decBb[(bk + k) * 96 + (r - 96)];
        else if (r == 192) v = enc_a[k];
        else if (r == 193) v = dec_a[k];
        else if (r == 194) v = ft[3 + kk];
      } else {
        const int r2 = i - (nb << 8);
        v = (r2 < 96) ? qb[r2] : (r2 < 192) ? kb[r2 - 96] : (r2 < 288) ? vb[r2 - 192] : ob[r2 - 288];
      }
      stage[i] = v;
    }
  }

  const float* spL = spin + b * 64 * FT + f * 1000 + tcl;
  const float* mxL = mix  + b * 96 * FT + f * 1000 + tcl;

  bh8 spb[2];
  {
    float spf[16];
    #pragma unroll
    for (int j = 0; j < 8; ++j) spf[j]     = __builtin_nontemporal_load(spL + (g * 8 + j) * FT);
    #pragma unroll
    for (int j = 0; j < 8; ++j) spf[8 + j] = __builtin_nontemporal_load(spL + (32 + g * 8 + j) * FT);
    #pragma unroll
    for (int kt = 0; kt < 2; ++kt)
      #pragma unroll
      for (int j = 0; j < 8; ++j) spb[kt][j] = (short)b16u(spf[kt * 8 + j]);
  }

  bh8 pre[6];
  load6s(pre, enc16 + k0 * 6144 + lb, 2);

  __syncthreads();

  f4 macc[6];
  #pragma unroll
  for (int mt = 0; mt < 6; ++mt) macc[mt] = (f4){0.f, 0.f, 0.f, 0.f};

  const int oo = g * 4;

  for (int kk = 0; kk < nb; ++kk) {
    const int k = k0 + kk;
    const unsigned short* ew  = enc16 + k * 6144 + lb;
    const unsigned short* dwp = dec16b + (bk + k) * 9216 + lb;
    const float* stg = stage + (kk << 8);

    f4 acc[6];
    init6(acc, stg, oo);
    #pragma unroll
    for (int mt = 0; mt < 6; ++mt)
      acc[mt] = __builtin_amdgcn_mfma_f32_16x16x32_bf16(pre[mt], spb[0], acc[mt], 0, 0, 0);
    #pragma unroll
    for (int mt = 0; mt < 6; ++mt) {
      const bh8 af = *reinterpret_cast<const bh8*>(ew + ((mt * 2 + 1) << 9));
      acc[mt] = __builtin_amdgcn_mfma_f32_16x16x32_bf16(af, spb[1], acc[mt], 0, 0, 0);
    }

    load6s(pre, dwp, 3);

    float mean, rs;
    ln96(acc, mean, rs);
    const float ea = stg[192];
    #pragma unroll
    for (int mt = 0; mt < 6; ++mt) {
      float x0 = (acc[mt][0] - mean) * rs; x0 = (x0 >= 0.f) ? x0 : ea * x0;
      float x1 = (acc[mt][1] - mean) * rs; x1 = (x1 >= 0.f) ? x1 : ea * x1;
      float x2 = (acc[mt][2] - mean) * rs; x2 = (x2 >= 0.f) ? x2 : ea * x2;
      float x3 = (acc[mt][3] - mean) * rs; x3 = (x3 >= 0.f) ? x3 : ea * x3;
      uint2 u;
      u.x = pk2(x0, x1);
      u.y = pk2(x2, x3);
      *reinterpret_cast<uint2*>(xw + ((mt * 16 + oo) ^ sw)) = u;
    }
    LDSWAIT;

    f4 dacc[6];
    init6(dacc, stg + 96, oo);
    {
      const bh8 bf0 = *reinterpret_cast<const bh8*>(xw + ((0 * 32 + g * 8) ^ sw));
      #pragma unroll
      for (int mt = 0; mt < 6; ++mt)
        dacc[mt] = __builtin_amdgcn_mfma_f32_16x16x32_bf16(pre[mt], bf0, dacc[mt], 0, 0, 0);
    }

    {
      const bool more = (kk + 1 < nb);
      load6s(pre, more ? (enc16 + (k + 1) * 6144 + lb) : (q16 + lb), more ? 2 : 3);
    }

    #pragma unroll
    for (int kt = 1; kt < 3; ++kt) {
      const bh8 bf = *reinterpret_cast<const bh8*>(xw + ((kt * 32 + g * 8) ^ sw));
      #pragma unroll
      for (int mt = 0; mt < 6; ++mt) {
        const bh8 af = *reinterpret_cast<const bh8*>(dwp + ((mt * 3 + kt) << 9));
        dacc[mt] = __builtin_amdgcn_mfma_f32_16x16x32_bf16(af, bf, dacc[mt], 0, 0, 0);
      }
    }
    float mean2, rs2;
    ln96(dacc, mean2, rs2);
    const float da = stg[193];
    const float win = stg[194];
    #pragma unroll
    for (int mt = 0; mt < 6; ++mt)
      #pragma unroll
      for (int r = 0; r < 4; ++r) {
        float x = (dacc[mt][r] - mean2) * rs2;
        x = (x >= 0.f) ? x : da * x;
        macc[mt][r] = fmaf(win, x, macc[mt][r]);
      }
  }

  float mxf[24];
  #pragma unroll
  for (int kt = 0; kt < 3; ++kt)
    #pragma unroll
    for (int j = 0; j < 8; ++j) mxf[kt * 8 + j] = mxL[(kt * 32 + g * 8 + j) * FT];

  #pragma unroll
  for (int mt = 0; mt < 6; ++mt) {
    uint2 u;
    u.x = pk2(macc[mt][0] * winv, macc[mt][1] * winv);
    u.y = pk2(macc[mt][2] * winv, macc[mt][3] * winv);
    *reinterpret_cast<uint2*>(xw + ((mt * 16 + oo) ^ sw)) = u;
  }
  LDSWAIT;
  bh8 gfr[3];
  #pragma unroll
  for (int kt = 0; kt < 3; ++kt) gfr[kt] = *reinterpret_cast<const bh8*>(xw + ((kt * 32 + g * 8) ^ sw));

  bh8 mxb[3];
  #pragma unroll
  for (int kt = 0; kt < 3; ++kt)
    #pragma unroll
    for (int j = 0; j < 8; ++j) mxb[kt][j] = (short)b16u(mxf[kt * 8 + j]);

  const float* stQ = stage + (nb << 8);

  f4 qacc[6];
  init6(qacc, stQ, oo);
  const unsigned short* qp16 = q16 + lb;
  #pragma unroll
  for (int mt = 0; mt < 6; ++mt)
    qacc[mt] = __builtin_amdgcn_mfma_f32_16x16x32_bf16(pre[mt], mxb[0], qacc[mt], 0, 0, 0);
  load6s(pre, k16 + lb, 3);
  #pragma unroll
  for (int kt = 1; kt < 3; ++kt)
    #pragma unroll
    for (int mt = 0; mt < 6; ++mt) {
      const bh8 af = *reinterpret_cast<const bh8*>(qp16 + ((mt * 3 + kt) << 9));
      qacc[mt] = __builtin_amdgcn_mfma_f32_16x16x32_bf16(af, mxb[kt], qacc[mt], 0, 0, 0);
    }
  f4 kacc[6];
  init6(kacc, stQ + 96, oo);
  const unsigned short* kp16 = k16 + lb;
  #pragma unroll
  for (int mt = 0; mt < 6; ++mt)
    kacc[mt] = __builtin_amdgcn_mfma_f32_16x16x32_bf16(pre[mt], gfr[0], kacc[mt], 0, 0, 0);
  load6s(pre, v16 + lb, 3);
  #pragma unroll
  for (int kt = 1; kt < 3; ++kt)
    #pragma unroll
    for (int mt = 0; mt < 6; ++mt) {
      const bh8 af = *reinterpret_cast<const bh8*>(kp16 + ((mt * 3 + kt) << 9));
      kacc[mt] = __builtin_amdgcn_mfma_f32_16x16x32_bf16(af, gfr[kt], kacc[mt], 0, 0, 0);
    }
  float p0 = 0.f, p1 = 0.f;
  #pragma unroll
  for (int mt = 0; mt < 6; ++mt) {
    p0 = fmaf(qacc[mt][0], kacc[mt][0], p0);
    p1 = fmaf(qacc[mt][1], kacc[mt][1], p1);
    p0 = fmaf(qacc[mt][2], kacc[mt][2], p0);
    p1 = fmaf(qacc[mt][3], kacc[mt][3], p1);
  }
  float p = p0 + p1;
  p += __shfl_xor(p, 16); p += __shfl_xor(p, 32);
  const float sig = 1.f / (1.f + __expf(-p * 0.10206207261596575f));

  f4 vacc[6];
  init6(vacc, stQ + 192, oo);
  const unsigned short* vp16 = v16 + lb;
  #pragma unroll
  for (int mt = 0; mt < 6; ++mt)
    vacc[mt] = __builtin_amdgcn_mfma_f32_16x16x32_bf16(pre[mt], gfr[0], vacc[mt], 0, 0, 0);
  load6s(pre, o16 + lb, 3);
  #pragma unroll
  for (int kt = 1; kt < 3; ++kt)
    #pragma unroll
    for (int mt = 0; mt < 6; ++mt) {
      const bh8 af = *reinterpret_cast<const bh8*>(vp16 + ((mt * 3 + kt) << 9));
      vacc[mt] = __builtin_amdgcn_mfma_f32_16x16x32_bf16(af, gfr[kt], vacc[mt], 0, 0, 0);
    }
  #pragma unroll
  for (int mt = 0; mt < 6; ++mt) {
    uint2 u;
    u.x = pk2(vacc[mt][0] * sig, vacc[mt][1] * sig);
    u.y = pk2(vacc[mt][2] * sig, vacc[mt][3] * sig);
    *reinterpret_cast<uint2*>(xw + ((mt * 16 + oo) ^ sw)) = u;
  }
  LDSWAIT;
  bh8 afr[3];
  #pragma unroll
  for (int kt = 0; kt < 3; ++kt) afr[kt] = *reinterpret_cast<const bh8*>(xw + ((kt * 32 + g * 8) ^ sw));

  f4 oacc[6];
  init6(oacc, stQ + 288, oo);
  const unsigned short* op16 = o16 + lb;
  #pragma unroll
  for (int mt = 0; mt < 6; ++mt)
    oacc[mt] = __builtin_amdgcn_mfma_f32_16x16x32_bf16(pre[mt], afr[0], oacc[mt], 0, 0, 0);
  #pragma unroll
  for (int kt = 1; kt < 3; ++kt)
    #pragma unroll
    for (int mt = 0; mt < 6; ++mt) {
      const bh8 af = *reinterpret_cast<const bh8*>(op16 + ((mt * 3 + kt) << 9));
      oacc[mt] = __builtin_amdgcn_mfma_f32_16x16x32_bf16(af, afr[kt], oacc[mt], 0, 0, 0);
    }

  __syncthreads();

  #pragma unroll
  for (int mt = 0; mt < 6; ++mt)
    #pragma unroll
    for (int r = 0; r < 4; ++r)
      OS[(mt * 16 + oo + r) * 68 + col] = oacc[mt][r];

  __syncthreads();

  const int cvalid = 1000 - t0;
  if (cvalid >= 64) {
    #pragma unroll
    for (int it = 0; it < 6; ++it) {
      const int i   = it * 256 + tid;
      const int row = i >> 4;
      const int c4  = (i & 15) << 2;
      f4v v = *reinterpret_cast<const f4v*>(&OS[row * 68 + c4]);
      const long gi = (long)(b * 96 + row) * FT + f * 1000 + t0 + c4;
      const f4v m = *reinterpret_cast<const f4v*>(mix + gi);
      v = v + m;
      __builtin_nontemporal_store(v, reinterpret_cast<f4v*>(out + gi));
    }
  } else {
    #pragma unroll
    for (int it = 0; it < 24; ++it) {
      const int i   = it * 256 + tid;
      const int row = i >> 6;
      const int c   = i & 63;
      if (c < cvalid) {
        const long gi = (long)(b * 96 + row) * FT + f * 1000 + t0 + c;
        __builtin_nontemporal_store(OS[row * 68 + c] + mix[gi], out + gi);
      }
    }
  }
}

extern "C" void kernel_launch(void* const* d_in, const int* in_sizes, int n_in,
                              void* d_out, int out_size, void* d_ws, size_t ws_size,
                              hipStream_t stream) {
  (void)in_sizes; (void)n_in; (void)out_size;
  const float* mix   = (const float*)d_in[0];
  const float* spin  = (const float*)d_in[1];
  const float* doa   = (const float*)d_in[2];
  const float* enc_w = (const float*)d_in[3];
  const float* enc_b = (const float*)d_in[4];
  const float* enc_a = (const float*)d_in[5];
  const float* dqg_w = (const float*)d_in[6];
  const float* dqg_b = (const float*)d_in[7];
  const float* dec_w = (const float*)d_in[8];
  const float* dec_b = (const float*)d_in[9];
  const float* dec_a = (const float*)d_in[10];
  const float* qw    = (const float*)d_in[11];
  const float* qb    = (const float*)d_in[12];
  const float* kw    = (const float*)d_in[13];
  const float* kb    = (const float*)d_in[14];
  const float* vw    = (const float*)d_in[15];
  const float* vb    = (const float*)d_in[16];
  const float* oww   = (const float*)d_in[17];
  const float* obb   = (const float*)d_in[18];
  float* outp = (float*)d_out;

  unsigned short* w16 = (unsigned short*)d_ws;
  unsigned short* enc16 = w16;
  unsigned short* q16   = w16 + 476160;
  unsigned short* k16   = q16 + 9216;
  unsigned short* v16   = k16 + 9216;
  unsigned short* o16   = v16 + 9216;
  float* gbws = (float*)((char*)d_ws + 1026048);
  float* ftab = (float*)((char*)d_ws + 1121280);
  unsigned short* dec16b = (unsigned short*)((char*)d_ws + 1129504);
  float* decBb = (float*)((char*)d_ws + 3415072);
  bh8* gfrag  = (bh8*)((char*)d_ws + 3462720);   // 16448*768*16 = 202,113,024 B
  const size_t need = 3462720ull + 202113024ull;

  hipLaunchKernelGGL(prep_w, dim3(512), dim3(256), 0, stream,
                     enc_w, dec_w, qw, kw, vw, oww, w16);
  hipLaunchKernelGGL(qp_kernel, dim3(NBANDS, 4), dim3(192), 0, stream,
                     doa, dqg_w, dqg_b, gbws);
  hipLaunchKernelGGL(prep_dec, dim3(NBANDS, 4), dim3(96), 0, stream,
                     dec_w, dec_b, gbws, dec16b, decBb);
  hipLaunchKernelGGL(tab_kernel, dim3(1), dim3(320), 0, stream, ftab);

  if (ws_size >= need) {
    hipLaunchKernelGGL(band_mfma, dim3(16448), dim3(256), 0, stream,
                       spin, enc16, enc_b, enc_a, dec16b, decBb, dec_a, ftab, gfrag);
    hipLaunchKernelGGL(qkvo_mfma, dim3(16448), dim3(256), 0, stream,
                       mix, gfrag, q16, qb, k16, kb, v16, vb, o16, obb, outp);
  } else {
    hipLaunchKernelGGL(fused_mfma, dim3(16448), dim3(256), 0, stream,
                       mix, spin, enc16, enc_b, enc_a, dec16b, decBb, dec_a, ftab,
                       q16, qb, k16, kb, v16, vb, o16, obb, outp);
  }
}

// Round 18
// 637.467 us; speedup vs baseline: 1.0413x; 1.0413x over previous
//
#include <hip/hip_runtime.h>
#include <math.h>

#define NBANDS 31
#define FT 257000

typedef __attribute__((ext_vector_type(8))) short bh8;
typedef __attribute__((ext_vector_type(4))) float f4;
typedef __attribute__((ext_vector_type(4))) float f4v;

__constant__ int d_bs[NBANDS] = {0,1,1,2,2,2,3,3,4,5,6,7,8,10,11,13,16,19,23,27,32,38,45,54,64,76,91,108,128,152,181};
__constant__ int d_be[NBANDS] = {2,3,3,3,4,4,5,6,7,8,9,11,12,14,17,20,24,28,33,39,46,55,65,77,92,109,129,153,182,216,257};

__device__ __forceinline__ unsigned short b16u(float v) {
  __bf16 h = (__bf16)v;
  return __builtin_bit_cast(unsigned short, h);
}
__device__ __forceinline__ unsigned pk2(float a, float b) {
  return (unsigned)b16u(a) | ((unsigned)b16u(b) << 16);
}
__device__ __forceinline__ float hann1(int i, int L) {
  return 0.5f - 0.5f * cosf(6.283185307179586f * (float)i / (float)L);
}

// ---- weight f32 -> bf16 prep, permuted into MFMA-fragment order (enc + qkvo) ----
__global__ __launch_bounds__(256) void prep_w(
    const float* __restrict__ enc_w, const float* __restrict__ dec_w,
    const float* __restrict__ qw, const float* __restrict__ kw,
    const float* __restrict__ vw, const float* __restrict__ ow,
    unsigned short* __restrict__ w16) {
  const int stride = gridDim.x * blockDim.x;
  for (int i = blockIdx.x * blockDim.x + threadIdx.x; i < 513024; i += stride) {
    float v;
    if (i < 190464) {                      // enc: K=64, KT=2
      const int k = i / 6144, r = i - k * 6144;
      const int tile = r >> 9, li = r & 511;
      const int lane = li >> 3, j = li & 7;
      const int g = lane >> 4, n = lane & 15;
      const int mt = tile >> 1, kt = tile & 1;
      v = enc_w[k * 6144 + (mt * 16 + n) * 64 + kt * 32 + g * 8 + j];
    } else if (i < 476160) {               // legacy dec slot (unused)
      const int i2 = i - 190464;
      const int k = i2 / 9216, r = i2 - k * 9216;
      const int tile = r >> 9, li = r & 511;
      const int lane = li >> 3, j = li & 7;
      const int g = lane >> 4, n = lane & 15;
      const int mt = tile / 3, kt = tile - mt * 3;
      v = dec_w[k * 9216 + (mt * 16 + n) * 96 + kt * 32 + g * 8 + j];
    } else {                               // q,k,v,o
      const int i2 = i - 476160;
      const int a = i2 / 9216, r = i2 - a * 9216;
      const int tile = r >> 9, li = r & 511;
      const int lane = li >> 3, j = li & 7;
      const int g = lane >> 4, n = lane & 15;
      const int mt = tile / 3, kt = tile - mt * 3;
      const float* src = (a == 0) ? qw : (a == 1) ? kw : (a == 2) ? vw : ow;
      v = src[(mt * 16 + n) * 96 + kt * 32 + g * 8 + j];
    }
    w16[i] = b16u(v);
  }
}

__global__ __launch_bounds__(192) void qp_kernel(const float* __restrict__ doa,
                                                 const float* __restrict__ dqg_w,
                                                 const float* __restrict__ dqg_b,
                                                 float* __restrict__ gbuf) {
  const int k = blockIdx.x, b = blockIdx.y;
  const int tid = threadIdx.x;
  __shared__ float sdoa[36];
  if (tid < 36) sdoa[tid] = doa[b * 36 + tid];
  __syncthreads();
  const float* wr = dqg_w + (k * 192 + tid) * 36;
  float acc = dqg_b[k * 192 + tid];
  #pragma unroll
  for (int i = 0; i < 36; ++i) acc = fmaf(wr[i], sdoa[i], acc);
  if (tid < 96) acc += 1.0f;
  gbuf[(k * 4 + b) * 192 + tid] = acc;
}

// ---- FiLM fold ----
__global__ __launch_bounds__(96) void prep_dec(
    const float* __restrict__ dec_w, const float* __restrict__ dec_b,
    const float* __restrict__ gbuf,
    unsigned short* __restrict__ dec16b, float* __restrict__ decBb) {
  const int k = blockIdx.x, b = blockIdx.y;
  const int o = threadIdx.x;
  __shared__ float gm[96], bt[96];
  gm[o] = gbuf[(k * 4 + b) * 192 + o];
  bt[o] = gbuf[(k * 4 + b) * 192 + 96 + o];
  __syncthreads();
  const float* wr = dec_w + k * 9216 + o * 96;
  float bias = dec_b[k * 96 + o];
  unsigned short* dst = dec16b + (b * 31 + k) * 9216;
  const int mt = o >> 4, n = o & 15;
  for (int c = 0; c < 96; ++c) {
    const float wv = wr[c];
    bias = fmaf(wv, bt[c], bias);
    const int kt = c >> 5, g = (c & 31) >> 3, j = c & 7;
    dst[((mt * 3 + kt) << 9) + (((g << 4) + n) << 3) + j] = b16u(wv * gm[c]);
  }
  decBb[(b * 31 + k) * 96 + o] = bias;
}

// ---- per-f table ----
__global__ __launch_bounds__(320) void tab_kernel(float* __restrict__ ftab) {
  const int f = blockIdx.x * blockDim.x + threadIdx.x;
  if (f >= 257) return;
  int k0 = 0; while (d_be[k0] <= f) ++k0;
  int k1 = k0; while (k1 < NBANDS && d_bs[k1] <= f) ++k1;
  float wsum = 0.f, wn[5];
  for (int k = k0; k < k1; ++k) {
    const float wv = hann1(f - d_bs[k], d_be[k] - d_bs[k]);
    wn[k - k0] = wv; wsum += wv;
  }
  float* o = ftab + f * 8;
  o[0] = (float)k0; o[1] = (float)(k1 - k0); o[2] = 1.0f / fmaxf(wsum, 1e-8f);
  #pragma unroll
  for (int j = 0; j < 5; ++j) o[3 + j] = (j < k1 - k0) ? wn[j] : 0.f;
}

#define LDSWAIT asm volatile("s_waitcnt lgkmcnt(0)" ::: "memory")

__device__ __forceinline__ void init6(f4* acc, const float* s, int off) {
  #pragma unroll
  for (int mt = 0; mt < 6; ++mt) {
    const float4 bb = *reinterpret_cast<const float4*>(s + mt * 16 + off);
    acc[mt] = (f4){bb.x, bb.y, bb.z, bb.w};
  }
}
__device__ __forceinline__ void ln96(const f4* acc, float& mean, float& rs) {
  float s0 = 0.f, s1 = 0.f, s2 = 0.f, s3 = 0.f;
  float q0 = 0.f, q1 = 0.f, q2 = 0.f, q3 = 0.f;
  #pragma unroll
  for (int mt = 0; mt < 6; ++mt) {
    const float a0 = acc[mt][0], a1 = acc[mt][1], a2 = acc[mt][2], a3 = acc[mt][3];
    s0 += a0; s1 += a1; s2 += a2; s3 += a3;
    q0 = fmaf(a0, a0, q0); q1 = fmaf(a1, a1, q1);
    q2 = fmaf(a2, a2, q2); q3 = fmaf(a3, a3, q3);
  }
  float sm = (s0 + s1) + (s2 + s3);
  float sq = (q0 + q1) + (q2 + q3);
  sm += __shfl_xor(sm, 16); sm += __shfl_xor(sm, 32);
  sq += __shfl_xor(sq, 16); sq += __shfl_xor(sq, 32);
  mean = sm * (1.f / 96.f);
  rs = rsqrtf(sq * (1.f / 96.f) - mean * mean + 1e-5f);
}
__device__ __forceinline__ void load6s(bh8* dst, const unsigned short* p, int step9) {
  #pragma unroll
  for (int mt = 0; mt < 6; ++mt)
    dst[mt] = *reinterpret_cast<const bh8*>(p + ((mt * step9) << 9));
}

// ---- monolith; two-band software-pipelined band loop (enc(k+1) overlaps LN2(k)) ----
__global__ __launch_bounds__(256, 3) void fused_mfma(
    const float* __restrict__ mix, const float* __restrict__ spin,
    const unsigned short* __restrict__ enc16, const float* __restrict__ enc_b, const float* __restrict__ enc_a,
    const unsigned short* __restrict__ dec16b, const float* __restrict__ decBb, const float* __restrict__ dec_a,
    const float* __restrict__ ftab,
    const unsigned short* __restrict__ q16, const float* __restrict__ qb,
    const unsigned short* __restrict__ k16, const float* __restrict__ kb,
    const unsigned short* __restrict__ v16, const float* __restrict__ vb,
    const unsigned short* __restrict__ o16, const float* __restrict__ ob,
    float* __restrict__ out) {
  const int id0 = (int)blockIdx.x;
  const int id  = (id0 & 7) * 2056 + (id0 >> 3);   // bijective XCD swizzle (16448 = 8*2056)
  const int tt  = id & 15;
  const int fb  = id >> 4;
  const int f   = fb % 257;
  const int b   = fb / 257;
  const int t0  = tt << 6;

  const int tid  = threadIdx.x;
  const int lane = tid & 63;
  const int w    = tid >> 6;
  const int g    = lane >> 4;
  const int n    = lane & 15;
  const int col  = (w << 4) + n;
  const int t    = t0 + col;
  const int tcl  = (t < 1000) ? t : 999;
  const int sw   = (n & 7) << 3;
  const int lb   = lane << 3;
  const int bk   = b * 31;

  // LDS pool: [XT 16384B][stage 6656B]; OS (96*68*4=26112B) aliases from 0
  __shared__ __align__(16) char smem[26112];
  unsigned short* XT = (unsigned short*)smem;
  float* stage = (float*)(smem + 16384);
  float* OS = (float*)smem;
  unsigned short* xw = XT + col * 128;

  const float* ft = ftab + f * 8;
  const int k0 = (int)ft[0];
  const int nb = (int)ft[1];
  const float winv = ft[2];

  // cooperative stage: per band (stride 256): encB96|decB'96|ea,da,win ; tail: qb|kb|vb|ob
  {
    const int tot = (nb << 8) + 384;
    for (int i = tid; i < tot; i += 256) {
      const int kk = i >> 8, r = i & 255;
      float v = 0.f;
      if (kk < nb) {
        const int k = k0 + kk;
        if      (r < 96)  v = enc_b[k * 96 + r];
        else if (r < 192) v = decBb[(bk + k) * 96 + (r - 96)];
        else if (r == 192) v = enc_a[k];
        else if (r == 193) v = dec_a[k];
        else if (r == 194) v = ft[3 + kk];
      } else {
        const int r2 = i - (nb << 8);
        v = (r2 < 96) ? qb[r2] : (r2 < 192) ? kb[r2 - 96] : (r2 < 288) ? vb[r2 - 192] : ob[r2 - 288];
      }
      stage[i] = v;
    }
  }

  const float* spL = spin + b * 64 * FT + f * 1000 + tcl;
  const float* mxL = mix  + b * 96 * FT + f * 1000 + tcl;

  // spin prefetch (read-once)
  bh8 spb[2];
  {
    float spf[16];
    #pragma unroll
    for (int j = 0; j < 8; ++j) spf[j]     = __builtin_nontemporal_load(spL + (g * 8 + j) * FT);
    #pragma unroll
    for (int j = 0; j < 8; ++j) spf[8 + j] = __builtin_nontemporal_load(spL + (32 + g * 8 + j) * FT);
    #pragma unroll
    for (int kt = 0; kt < 2; ++kt)
      #pragma unroll
      for (int j = 0; j < 8; ++j) spb[kt][j] = (short)b16u(spf[kt * 8 + j]);
  }

  // rotating prefetch buffer: enc g0 of first band
  bh8 pre[6];
  load6s(pre, enc16 + k0 * 6144 + lb, 2);

  __syncthreads();   // stage visible

  f4 macc[6];
  #pragma unroll
  for (int mt = 0; mt < 6; ++mt) macc[mt] = (f4){0.f, 0.f, 0.f, 0.f};

  const int oo = g * 4;

  // ---- prologue: enc(k0) into acc; pre -> dec g0(k0) ----
  f4 acc[6];
  {
    const unsigned short* ew = enc16 + k0 * 6144 + lb;
    init6(acc, stage, oo);
    #pragma unroll
    for (int mt = 0; mt < 6; ++mt)
      acc[mt] = __builtin_amdgcn_mfma_f32_16x16x32_bf16(pre[mt], spb[0], acc[mt], 0, 0, 0);
    #pragma unroll
    for (int mt = 0; mt < 6; ++mt) {
      const bh8 af = *reinterpret_cast<const bh8*>(ew + ((mt * 2 + 1) << 9));
      acc[mt] = __builtin_amdgcn_mfma_f32_16x16x32_bf16(af, spb[1], acc[mt], 0, 0, 0);
    }
    load6s(pre, dec16b + (bk + k0) * 9216 + lb, 3);
  }

  // ---- band loop; INV at entry: acc = enc-out(k), pre = dec'g0(k) ----
  for (int kk = 0; kk < nb; ++kk) {
    const int k = k0 + kk;
    const unsigned short* dwp = dec16b + (bk + k) * 9216 + lb;
    const float* stg = stage + (kk << 8);
    const bool more = (kk + 1 < nb);

    // LN1 + prelu -> tgt -> XT (FiLM folded into dec')
    float mean, rs;
    ln96(acc, mean, rs);
    const float ea = stg[192];
    #pragma unroll
    for (int mt = 0; mt < 6; ++mt) {
      float x0 = (acc[mt][0] - mean) * rs; x0 = (x0 >= 0.f) ? x0 : ea * x0;
      float x1 = (acc[mt][1] - mean) * rs; x1 = (x1 >= 0.f) ? x1 : ea * x1;
      float x2 = (acc[mt][2] - mean) * rs; x2 = (x2 >= 0.f) ? x2 : ea * x2;
      float x3 = (acc[mt][3] - mean) * rs; x3 = (x3 >= 0.f) ? x3 : ea * x3;
      uint2 u;
      u.x = pk2(x0, x1);
      u.y = pk2(x2, x3);
      *reinterpret_cast<uint2*>(xw + ((mt * 16 + oo) ^ sw)) = u;
    }
    LDSWAIT;

    // dec': kt0 from pre
    f4 dacc[6];
    init6(dacc, stg + 96, oo);
    {
      const bh8 bf0 = *reinterpret_cast<const bh8*>(xw + ((0 * 32 + g * 8) ^ sw));
      #pragma unroll
      for (int mt = 0; mt < 6; ++mt)
        dacc[mt] = __builtin_amdgcn_mfma_f32_16x16x32_bf16(pre[mt], bf0, dacc[mt], 0, 0, 0);
    }
    // pre -> enc g0(k+1) (or Q g0)
    load6s(pre, more ? (enc16 + (k + 1) * 6144 + lb) : (q16 + lb), more ? 2 : 3);

    #pragma unroll
    for (int kt = 1; kt < 3; ++kt) {
      const bh8 bf = *reinterpret_cast<const bh8*>(xw + ((kt * 32 + g * 8) ^ sw));
      #pragma unroll
      for (int mt = 0; mt < 6; ++mt) {
        const bh8 af = *reinterpret_cast<const bh8*>(dwp + ((mt * 3 + kt) << 9));
        dacc[mt] = __builtin_amdgcn_mfma_f32_16x16x32_bf16(af, bf, dacc[mt], 0, 0, 0);
      }
    }

    // ---- enc(k+1) issued BEFORE LN2(k): independent MFMAs overlap the serial chain ----
    if (more) {
      const unsigned short* ew2 = enc16 + (k + 1) * 6144 + lb;
      f4 acc2[6];
      init6(acc2, stage + ((kk + 1) << 8), oo);
      #pragma unroll
      for (int mt = 0; mt < 6; ++mt)
        acc2[mt] = __builtin_amdgcn_mfma_f32_16x16x32_bf16(pre[mt], spb[0], acc2[mt], 0, 0, 0);
      #pragma unroll
      for (int mt = 0; mt < 6; ++mt) {
        const bh8 af = *reinterpret_cast<const bh8*>(ew2 + ((mt * 2 + 1) << 9));
        acc2[mt] = __builtin_amdgcn_mfma_f32_16x16x32_bf16(af, spb[1], acc2[mt], 0, 0, 0);
      }
      // pre -> dec' g0(k+1)
      load6s(pre, dec16b + (bk + k + 1) * 9216 + lb, 3);

      float mean2, rs2;
      ln96(dacc, mean2, rs2);
      const float da = stg[193];
      const float win = stg[194];
      #pragma unroll
      for (int mt = 0; mt < 6; ++mt)
        #pragma unroll
        for (int r = 0; r < 4; ++r) {
          float x = (dacc[mt][r] - mean2) * rs2;
          x = (x >= 0.f) ? x : da * x;
          macc[mt][r] = fmaf(win, x, macc[mt][r]);
        }
      #pragma unroll
      for (int mt = 0; mt < 6; ++mt) acc[mt] = acc2[mt];
    } else {
      float mean2, rs2;
      ln96(dacc, mean2, rs2);
      const float da = stg[193];
      const float win = stg[194];
      #pragma unroll
      for (int mt = 0; mt < 6; ++mt)
        #pragma unroll
        for (int r = 0; r < 4; ++r) {
          float x = (dacc[mt][r] - mean2) * rs2;
          x = (x >= 0.f) ? x : da * x;
          macc[mt][r] = fmaf(win, x, macc[mt][r]);
        }
    }
  }

  // ---- mix loads (cached; fragment pass) ----
  float mxf[24];
  #pragma unroll
  for (int kt = 0; kt < 3; ++kt)
    #pragma unroll
    for (int j = 0; j < 8; ++j) mxf[kt * 8 + j] = mxL[(kt * 32 + g * 8 + j) * FT];

  // ---- merged -> XT ----
  #pragma unroll
  for (int mt = 0; mt < 6; ++mt) {
    uint2 u;
    u.x = pk2(macc[mt][0] * winv, macc[mt][1] * winv);
    u.y = pk2(macc[mt][2] * winv, macc[mt][3] * winv);
    *reinterpret_cast<uint2*>(xw + ((mt * 16 + oo) ^ sw)) = u;
  }
  LDSWAIT;
  bh8 gfr[3];
  #pragma unroll
  for (int kt = 0; kt < 3; ++kt) gfr[kt] = *reinterpret_cast<const bh8*>(xw + ((kt * 32 + g * 8) ^ sw));

  bh8 mxb[3];
  #pragma unroll
  for (int kt = 0; kt < 3; ++kt)
    #pragma unroll
    for (int j = 0; j < 8; ++j) mxb[kt][j] = (short)b16u(mxf[kt * 8 + j]);

  const float* stQ = stage + (nb << 8);

  // ---- Q: kt0 from pre; refill pre <- K g0 ----
  f4 qacc[6];
  init6(qacc, stQ, oo);
  const unsigned short* qp16 = q16 + lb;
  #pragma unroll
  for (int mt = 0; mt < 6; ++mt)
    qacc[mt] = __builtin_amdgcn_mfma_f32_16x16x32_bf16(pre[mt], mxb[0], qacc[mt], 0, 0, 0);
  load6s(pre, k16 + lb, 3);
  #pragma unroll
  for (int kt = 1; kt < 3; ++kt)
    #pragma unroll
    for (int mt = 0; mt < 6; ++mt) {
      const bh8 af = *reinterpret_cast<const bh8*>(qp16 + ((mt * 3 + kt) << 9));
      qacc[mt] = __builtin_amdgcn_mfma_f32_16x16x32_bf16(af, mxb[kt], qacc[mt], 0, 0, 0);
    }
  // ---- K: kt0 from pre; refill pre <- V g0 ----
  f4 kacc[6];
  init6(kacc, stQ + 96, oo);
  const unsigned short* kp16 = k16 + lb;
  #pragma unroll
  for (int mt = 0; mt < 6; ++mt)
    kacc[mt] = __builtin_amdgcn_mfma_f32_16x16x32_bf16(pre[mt], gfr[0], kacc[mt], 0, 0, 0);
  load6s(pre, v16 + lb, 3);
  #pragma unroll
  for (int kt = 1; kt < 3; ++kt)
    #pragma unroll
    for (int mt = 0; mt < 6; ++mt) {
      const bh8 af = *reinterpret_cast<const bh8*>(kp16 + ((mt * 3 + kt) << 9));
      kacc[mt] = __builtin_amdgcn_mfma_f32_16x16x32_bf16(af, gfr[kt], kacc[mt], 0, 0, 0);
    }
  float p0 = 0.f, p1 = 0.f;
  #pragma unroll
  for (int mt = 0; mt < 6; ++mt) {
    p0 = fmaf(qacc[mt][0], kacc[mt][0], p0);
    p1 = fmaf(qacc[mt][1], kacc[mt][1], p1);
    p0 = fmaf(qacc[mt][2], kacc[mt][2], p0);
    p1 = fmaf(qacc[mt][3], kacc[mt][3], p1);
  }
  float p = p0 + p1;
  p += __shfl_xor(p, 16); p += __shfl_xor(p, 32);
  const float sig = 1.f / (1.f + __expf(-p * 0.10206207261596575f));

  // ---- V: kt0 from pre; refill pre <- O g0 ----
  f4 vacc[6];
  init6(vacc, stQ + 192, oo);
  const unsigned short* vp16 = v16 + lb;
  #pragma unroll
  for (int mt = 0; mt < 6; ++mt)
    vacc[mt] = __builtin_amdgcn_mfma_f32_16x16x32_bf16(pre[mt], gfr[0], vacc[mt], 0, 0, 0);
  load6s(pre, o16 + lb, 3);
  #pragma unroll
  for (int kt = 1; kt < 3; ++kt)
    #pragma unroll
    for (int mt = 0; mt < 6; ++mt) {
      const bh8 af = *reinterpret_cast<const bh8*>(vp16 + ((mt * 3 + kt) << 9));
      vacc[mt] = __builtin_amdgcn_mfma_f32_16x16x32_bf16(af, gfr[kt], vacc[mt], 0, 0, 0);
    }
  #pragma unroll
  for (int mt = 0; mt < 6; ++mt) {
    uint2 u;
    u.x = pk2(vacc[mt][0] * sig, vacc[mt][1] * sig);
    u.y = pk2(vacc[mt][2] * sig, vacc[mt][3] * sig);
    *reinterpret_cast<uint2*>(xw + ((mt * 16 + oo) ^ sw)) = u;
  }
  LDSWAIT;
  bh8 afr[3];
  #pragma unroll
  for (int kt = 0; kt < 3; ++kt) afr[kt] = *reinterpret_cast<const bh8*>(xw + ((kt * 32 + g * 8) ^ sw));

  // ---- O: kt0 from pre ----
  f4 oacc[6];
  init6(oacc, stQ + 288, oo);
  const unsigned short* op16 = o16 + lb;
  #pragma unroll
  for (int mt = 0; mt < 6; ++mt)
    oacc[mt] = __builtin_amdgcn_mfma_f32_16x16x32_bf16(pre[mt], afr[0], oacc[mt], 0, 0, 0);
  #pragma unroll
  for (int kt = 1; kt < 3; ++kt)
    #pragma unroll
    for (int mt = 0; mt < 6; ++mt) {
      const bh8 af = *reinterpret_cast<const bh8*>(op16 + ((mt * 3 + kt) << 9));
      oacc[mt] = __builtin_amdgcn_mfma_f32_16x16x32_bf16(af, afr[kt], oacc[mt], 0, 0, 0);
    }

  __syncthreads();   // ALL waves done with XT/stage before aliased OS writes

  #pragma unroll
  for (int mt = 0; mt < 6; ++mt)
    #pragma unroll
    for (int r = 0; r < 4; ++r)
      OS[(mt * 16 + oo + r) * 68 + col] = oacc[mt][r];

  __syncthreads();   // all waves' OS writes visible

  // ---- coalesced epilogue: residual add + NT store (float4 fast path) ----
  const int cvalid = 1000 - t0;
  if (cvalid >= 64) {
    #pragma unroll
    for (int it = 0; it < 6; ++it) {
      const int i   = it * 256 + tid;
      const int row = i >> 4;
      const int c4  = (i & 15) << 2;
      f4v v = *reinterpret_cast<const f4v*>(&OS[row * 68 + c4]);
      const long gi = (long)(b * 96 + row) * FT + f * 1000 + t0 + c4;
      const f4v m = *reinterpret_cast<const f4v*>(mix + gi);
      v = v + m;
      __builtin_nontemporal_store(v, reinterpret_cast<f4v*>(out + gi));
    }
  } else {
    #pragma unroll
    for (int it = 0; it < 24; ++it) {
      const int i   = it * 256 + tid;
      const int row = i >> 6;
      const int c   = i & 63;
      if (c < cvalid) {
        const long gi = (long)(b * 96 + row) * FT + f * 1000 + t0 + c;
        __builtin_nontemporal_store(OS[row * 68 + c] + mix[gi], out + gi);
      }
    }
  }
}

extern "C" void kernel_launch(void* const* d_in, const int* in_sizes, int n_in,
                              void* d_out, int out_size, void* d_ws, size_t ws_size,
                              hipStream_t stream) {
  (void)in_sizes; (void)n_in; (void)out_size; (void)ws_size;
  const float* mix   = (const float*)d_in[0];
  const float* spin  = (const float*)d_in[1];
  const float* doa   = (const float*)d_in[2];
  const float* enc_w = (const float*)d_in[3];
  const float* enc_b = (const float*)d_in[4];
  const float* enc_a = (const float*)d_in[5];
  const float* dqg_w = (const float*)d_in[6];
  const float* dqg_b = (const float*)d_in[7];
  const float* dec_w = (const float*)d_in[8];
  const float* dec_b = (const float*)d_in[9];
  const float* dec_a = (const float*)d_in[10];
  const float* qw    = (const float*)d_in[11];
  const float* qb    = (const float*)d_in[12];
  const float* kw    = (const float*)d_in[13];
  const float* kb    = (const float*)d_in[14];
  const float* vw    = (const float*)d_in[15];
  const float* vb    = (const float*)d_in[16];
  const float* oww   = (const float*)d_in[17];
  const float* obb   = (const float*)d_in[18];
  float* outp = (float*)d_out;

  unsigned short* w16 = (unsigned short*)d_ws;
  unsigned short* enc16 = w16;
  unsigned short* q16   = w16 + 476160;
  unsigned short* k16   = q16 + 9216;
  unsigned short* v16   = k16 + 9216;
  unsigned short* o16   = v16 + 9216;
  float* gbws = (float*)((char*)d_ws + 1026048);
  float* ftab = (float*)((char*)d_ws + 1121280);
  unsigned short* dec16b = (unsigned short*)((char*)d_ws + 1129504);
  float* decBb = (float*)((char*)d_ws + 3415072);

  hipLaunchKernelGGL(prep_w, dim3(512), dim3(256), 0, stream,
                     enc_w, dec_w, qw, kw, vw, oww, w16);
  hipLaunchKernelGGL(qp_kernel, dim3(NBANDS, 4), dim3(192), 0, stream,
                     doa, dqg_w, dqg_b, gbws);
  hipLaunchKernelGGL(prep_dec, dim3(NBANDS, 4), dim3(96), 0, stream,
                     dec_w, dec_b, gbws, dec16b, decBb);
  hipLaunchKernelGGL(tab_kernel, dim3(1), dim3(320), 0, stream, ftab);
  hipLaunchKernelGGL(fused_mfma, dim3(16448), dim3(256), 0, stream,
                     mix, spin, enc16, enc_b, enc_a, dec16b, decBb, dec_a, ftab,
                     q16, qb, k16, kb, v16, vb, o16, obb, outp);
}

// Round 19
// 540.534 us; speedup vs baseline: 1.2281x; 1.1793x over previous
//
#include <hip/hip_runtime.h>
#include <math.h>

#define NBANDS 31
#define FT 257000

typedef __attribute__((ext_vector_type(8))) short bh8;
typedef __attribute__((ext_vector_type(4))) float f4;

__constant__ int d_bs[NBANDS] = {0,1,1,2,2,2,3,3,4,5,6,7,8,10,11,13,16,19,23,27,32,38,45,54,64,76,91,108,128,152,181};
__constant__ int d_be[NBANDS] = {2,3,3,3,4,4,5,6,7,8,9,11,12,14,17,20,24,28,33,39,46,55,65,77,92,109,129,153,182,216,257};

__device__ __forceinline__ unsigned short b16u(float v) {
  __bf16 h = (__bf16)v;
  return __builtin_bit_cast(unsigned short, h);
}
__device__ __forceinline__ unsigned pk2(float a, float b) {
  return (unsigned)b16u(a) | ((unsigned)b16u(b) << 16);
}
__device__ __forceinline__ float hann1(int i, int L) {
  return 0.5f - 0.5f * cosf(6.283185307179586f * (float)i / (float)L);
}

// ---- weight f32 -> bf16 prep, permuted into MFMA-fragment order ----
__global__ __launch_bounds__(256) void prep_w(
    const float* __restrict__ enc_w, const float* __restrict__ dec_w,
    const float* __restrict__ qw, const float* __restrict__ kw,
    const float* __restrict__ vw, const float* __restrict__ ow,
    unsigned short* __restrict__ w16) {
  const int stride = gridDim.x * blockDim.x;
  for (int i = blockIdx.x * blockDim.x + threadIdx.x; i < 513024; i += stride) {
    float v;
    if (i < 190464) {                      // enc: K=64, KT=2
      const int k = i / 6144, r = i - k * 6144;
      const int tile = r >> 9, li = r & 511;
      const int lane = li >> 3, j = li & 7;
      const int g = lane >> 4, n = lane & 15;
      const int mt = tile >> 1, kt = tile & 1;
      v = enc_w[k * 6144 + (mt * 16 + n) * 64 + kt * 32 + g * 8 + j];
    } else if (i < 476160) {               // dec: K=96, KT=3
      const int i2 = i - 190464;
      const int k = i2 / 9216, r = i2 - k * 9216;
      const int tile = r >> 9, li = r & 511;
      const int lane = li >> 3, j = li & 7;
      const int g = lane >> 4, n = lane & 15;
      const int mt = tile / 3, kt = tile - mt * 3;
      v = dec_w[k * 9216 + (mt * 16 + n) * 96 + kt * 32 + g * 8 + j];
    } else {                               // q,k,v,o
      const int i2 = i - 476160;
      const int a = i2 / 9216, r = i2 - a * 9216;
      const int tile = r >> 9, li = r & 511;
      const int lane = li >> 3, j = li & 7;
      const int g = lane >> 4, n = lane & 15;
      const int mt = tile / 3, kt = tile - mt * 3;
      const float* src = (a == 0) ? qw : (a == 1) ? kw : (a == 2) ? vw : ow;
      v = src[(mt * 16 + n) * 96 + kt * 32 + g * 8 + j];
    }
    w16[i] = b16u(v);
  }
}

__global__ __launch_bounds__(192) void qp_kernel(const float* __restrict__ doa,
                                                 const float* __restrict__ dqg_w,
                                                 const float* __restrict__ dqg_b,
                                                 float* __restrict__ gbuf) {
  const int k = blockIdx.x, b = blockIdx.y;
  const int tid = threadIdx.x;
  __shared__ float sdoa[36];
  if (tid < 36) sdoa[tid] = doa[b * 36 + tid];
  __syncthreads();
  const float* wr = dqg_w + (k * 192 + tid) * 36;
  float acc = dqg_b[k * 192 + tid];
  #pragma unroll
  for (int i = 0; i < 36; ++i) acc = fmaf(wr[i], sdoa[i], acc);
  if (tid < 96) acc += 1.0f;
  gbuf[(k * 4 + b) * 192 + tid] = acc;
}

// ---- per-f table: {k0, nb, winv, win0..win4} ----
__global__ __launch_bounds__(320) void tab_kernel(float* __restrict__ ftab) {
  const int f = blockIdx.x * blockDim.x + threadIdx.x;
  if (f >= 257) return;
  int k0 = 0; while (d_be[k0] <= f) ++k0;
  int k1 = k0; while (k1 < NBANDS && d_bs[k1] <= f) ++k1;
  float wsum = 0.f, wn[5];
  for (int k = k0; k < k1; ++k) {
    const float wv = hann1(f - d_bs[k], d_be[k] - d_bs[k]);
    wn[k - k0] = wv; wsum += wv;
  }
  float* o = ftab + f * 8;
  o[0] = (float)k0; o[1] = (float)(k1 - k0); o[2] = 1.0f / fmaxf(wsum, 1e-8f);
  #pragma unroll
  for (int j = 0; j < 5; ++j) o[3 + j] = (j < k1 - k0) ? wn[j] : 0.f;
}

#define LDSWAIT asm volatile("s_waitcnt lgkmcnt(0)" ::: "memory")

__device__ __forceinline__ void init6(f4* acc, const float* s, int off) {
  #pragma unroll
  for (int mt = 0; mt < 6; ++mt) {
    const float4 bb = *reinterpret_cast<const float4*>(s + mt * 16 + off);
    acc[mt] = (f4){bb.x, bb.y, bb.z, bb.w};
  }
}
// tree-reduced LN over 24 per-lane values (+16/+32 shfl for 96-chan column)
__device__ __forceinline__ void ln96(const f4* acc, float& mean, float& rs) {
  float s0 = 0.f, s1 = 0.f, s2 = 0.f, s3 = 0.f;
  float q0 = 0.f, q1 = 0.f, q2 = 0.f, q3 = 0.f;
  #pragma unroll
  for (int mt = 0; mt < 6; ++mt) {
    const float a0 = acc[mt][0], a1 = acc[mt][1], a2 = acc[mt][2], a3 = acc[mt][3];
    s0 += a0; s1 += a1; s2 += a2; s3 += a3;
    q0 = fmaf(a0, a0, q0); q1 = fmaf(a1, a1, q1);
    q2 = fmaf(a2, a2, q2); q3 = fmaf(a3, a3, q3);
  }
  float sm = (s0 + s1) + (s2 + s3);
  float sq = (q0 + q1) + (q2 + q3);
  sm += __shfl_xor(sm, 16); sm += __shfl_xor(sm, 32);
  sq += __shfl_xor(sq, 16); sq += __shfl_xor(sq, 32);
  mean = sm * (1.f / 96.f);
  rs = rsqrtf(sq * (1.f / 96.f) - mean * mean + 1e-5f);
}
__device__ __forceinline__ void load6s(bh8* dst, const unsigned short* p, int step9) {
  #pragma unroll
  for (int mt = 0; mt < 6; ++mt)
    dst[mt] = *reinterpret_cast<const bh8*>(p + ((mt * step9) << 9));
}

// ---- fused MFMA kernel; aliased LDS (XT+stage / OS) ----
__global__ __launch_bounds__(256, 3) void fused_mfma(
    const float* __restrict__ mix, const float* __restrict__ spin,
    const unsigned short* __restrict__ enc16, const float* __restrict__ enc_b, const float* __restrict__ enc_a,
    const unsigned short* __restrict__ dec16, const float* __restrict__ dec_b, const float* __restrict__ dec_a,
    const float* __restrict__ gb, const float* __restrict__ ftab,
    const unsigned short* __restrict__ q16, const float* __restrict__ qb,
    const unsigned short* __restrict__ k16, const float* __restrict__ kb,
    const unsigned short* __restrict__ v16, const float* __restrict__ vb,
    const unsigned short* __restrict__ o16, const float* __restrict__ ob,
    float* __restrict__ out) {
  const int id0 = (int)blockIdx.x;
  const int id  = (id0 & 7) * 2056 + (id0 >> 3);   // bijective XCD swizzle (16448 = 8*2056)
  const int tt  = id & 15;
  const int fb  = id >> 4;
  const int f   = fb % 257;
  const int b   = fb / 257;
  const int t0  = tt << 6;

  const int tid  = threadIdx.x;
  const int lane = tid & 63;
  const int w    = tid >> 6;
  const int g    = lane >> 4;
  const int n    = lane & 15;
  const int col  = (w << 4) + n;
  const int t    = t0 + col;
  const bool tv  = t < 1000;
  const int tcl  = tv ? t : 999;
  const int sw   = (n & 7) << 3;
  const int lb   = lane << 3;

  // one LDS pool: [XT 16384B][stage 11776B]; OS (96*65*4=24960B) aliases from 0
  __shared__ __align__(16) char smem[28160];
  unsigned short* XT = (unsigned short*)smem;
  float* stage = (float*)(smem + 16384);
  float* OS = (float*)smem;
  unsigned short* xw = XT + col * 128;

  const float* ft = ftab + f * 8;
  const int k0 = (int)ft[0];
  const int nb = (int)ft[1];
  const float winv = ft[2];

  // cooperative stage: per band (stride 512): encB96|decB96|gb192|ea,da,win ; tail: qb|kb|vb|ob
  {
    const int tot = (nb << 9) + 384;
    for (int i = tid; i < tot; i += 256) {
      const int kk = i >> 9, r = i & 511;
      float v = 0.f;
      if (kk < nb) {
        const int k = k0 + kk;
        if      (r < 96)  v = enc_b[k * 96 + r];
        else if (r < 192) v = dec_b[k * 96 + (r - 96)];
        else if (r < 384) v = gb[(k * 4 + b) * 192 + (r - 192)];
        else if (r == 384) v = enc_a[k];
        else if (r == 385) v = dec_a[k];
        else if (r == 386) v = ft[3 + kk];
      } else {
        const int r2 = i - (nb << 9);
        v = (r2 < 96) ? qb[r2] : (r2 < 192) ? kb[r2 - 96] : (r2 < 288) ? vb[r2 - 192] : ob[r2 - 288];
      }
      stage[i] = v;
    }
  }

  const float* spL = spin + b * 64 * FT + f * 1000 + tcl;
  const float* mxL = mix  + b * 96 * FT + f * 1000 + tcl;

  // spin prefetch (read-once)
  bh8 spb[2];
  {
    float spf[16];
    #pragma unroll
    for (int j = 0; j < 8; ++j) spf[j]     = __builtin_nontemporal_load(spL + (g * 8 + j) * FT);
    #pragma unroll
    for (int j = 0; j < 8; ++j) spf[8 + j] = __builtin_nontemporal_load(spL + (32 + g * 8 + j) * FT);
    #pragma unroll
    for (int kt = 0; kt < 2; ++kt)
      #pragma unroll
      for (int j = 0; j < 8; ++j) spb[kt][j] = (short)b16u(spf[kt * 8 + j]);
  }

  // rotating prefetch buffer: enc g0 of first band
  bh8 pre[6];
  load6s(pre, enc16 + k0 * 6144 + lb, 2);

  __syncthreads();   // stage visible

  f4 macc[6];
  #pragma unroll
  for (int mt = 0; mt < 6; ++mt) macc[mt] = (f4){0.f, 0.f, 0.f, 0.f};

  const int oo = g * 4;

  // ---------------- band loop; INV: pre = enc g0(k) at entry ----------------
  for (int kk = 0; kk < nb; ++kk) {
    const int k = k0 + kk;
    const unsigned short* ew  = enc16 + k * 6144 + lb;
    const unsigned short* dwp = dec16 + k * 9216 + lb;
    const float* stg = stage + (kk << 9);

    // ---- enc: 96x64; kt=0 from pre, kt=1 inline ----
    f4 acc[6];
    init6(acc, stg, oo);
    #pragma unroll
    for (int mt = 0; mt < 6; ++mt)
      acc[mt] = __builtin_amdgcn_mfma_f32_16x16x32_bf16(pre[mt], spb[0], acc[mt], 0, 0, 0);
    #pragma unroll
    for (int mt = 0; mt < 6; ++mt) {
      const bh8 af = *reinterpret_cast<const bh8*>(ew + ((mt * 2 + 1) << 9));
      acc[mt] = __builtin_amdgcn_mfma_f32_16x16x32_bf16(af, spb[1], acc[mt], 0, 0, 0);
    }

    // pre dead -> refill with dec g0 (hides under LN1/FiLM)
    load6s(pre, dwp, 3);

    float mean, rs;
    ln96(acc, mean, rs);
    const float ea = stg[384];
    #pragma unroll
    for (int mt = 0; mt < 6; ++mt) {
      const float4 ga = *reinterpret_cast<const float4*>(stg + 192 + mt * 16 + oo);
      const float4 be = *reinterpret_cast<const float4*>(stg + 288 + mt * 16 + oo);
      float x0 = (acc[mt][0] - mean) * rs; x0 = (x0 >= 0.f) ? x0 : ea * x0;
      float x1 = (acc[mt][1] - mean) * rs; x1 = (x1 >= 0.f) ? x1 : ea * x1;
      float x2 = (acc[mt][2] - mean) * rs; x2 = (x2 >= 0.f) ? x2 : ea * x2;
      float x3 = (acc[mt][3] - mean) * rs; x3 = (x3 >= 0.f) ? x3 : ea * x3;
      uint2 u;
      u.x = pk2(fmaf(ga.x, x0, be.x), fmaf(ga.y, x1, be.y));
      u.y = pk2(fmaf(ga.z, x2, be.z), fmaf(ga.w, x3, be.w));
      *reinterpret_cast<uint2*>(xw + ((mt * 16 + g * 4) ^ sw)) = u;
    }
    LDSWAIT;

    // ---- dec: 96x96 from XT; kt=0 from pre ----
    f4 dacc[6];
    init6(dacc, stg + 96, oo);
    {
      const bh8 bf0 = *reinterpret_cast<const bh8*>(xw + ((0 * 32 + g * 8) ^ sw));
      #pragma unroll
      for (int mt = 0; mt < 6; ++mt)
        dacc[mt] = __builtin_amdgcn_mfma_f32_16x16x32_bf16(pre[mt], bf0, dacc[mt], 0, 0, 0);
    }

    // pre dead -> refill with next band's enc g0 (or Q g0)
    {
      const bool more = (kk + 1 < nb);
      load6s(pre, more ? (enc16 + (k + 1) * 6144 + lb) : (q16 + lb), more ? 2 : 3);
    }

    #pragma unroll
    for (int kt = 1; kt < 3; ++kt) {
      const bh8 bf = *reinterpret_cast<const bh8*>(xw + ((kt * 32 + g * 8) ^ sw));
      #pragma unroll
      for (int mt = 0; mt < 6; ++mt) {
        const bh8 af = *reinterpret_cast<const bh8*>(dwp + ((mt * 3 + kt) << 9));
        dacc[mt] = __builtin_amdgcn_mfma_f32_16x16x32_bf16(af, bf, dacc[mt], 0, 0, 0);
      }
    }
    float mean2, rs2;
    ln96(dacc, mean2, rs2);
    const float da = stg[385];
    const float win = stg[386];
    #pragma unroll
    for (int mt = 0; mt < 6; ++mt)
      #pragma unroll
      for (int r = 0; r < 4; ++r) {
        float x = (dacc[mt][r] - mean2) * rs2;
        x = (x >= 0.f) ? x : da * x;
        macc[mt][r] = fmaf(win, x, macc[mt][r]);
      }
  }

  // ---- mix loads (cached; residual re-read hits L1/L2) ----
  float mxf[24];
  #pragma unroll
  for (int kt = 0; kt < 3; ++kt)
    #pragma unroll
    for (int j = 0; j < 8; ++j) mxf[kt * 8 + j] = mxL[(kt * 32 + g * 8 + j) * FT];

  // ---- merged -> XT ----
  #pragma unroll
  for (int mt = 0; mt < 6; ++mt) {
    uint2 u;
    u.x = pk2(macc[mt][0] * winv, macc[mt][1] * winv);
    u.y = pk2(macc[mt][2] * winv, macc[mt][3] * winv);
    *reinterpret_cast<uint2*>(xw + ((mt * 16 + g * 4) ^ sw)) = u;
  }
  LDSWAIT;
  bh8 gfr[3];
  #pragma unroll
  for (int kt = 0; kt < 3; ++kt) gfr[kt] = *reinterpret_cast<const bh8*>(xw + ((kt * 32 + g * 8) ^ sw));

  bh8 mxb[3];
  #pragma unroll
  for (int kt = 0; kt < 3; ++kt)
    #pragma unroll
    for (int j = 0; j < 8; ++j) mxb[kt][j] = (short)b16u(mxf[kt * 8 + j]);

  const float* stQ = stage + (nb << 9);

  // ---- Q: kt0 from pre; refill pre <- K g0 ----
  f4 qacc[6];
  init6(qacc, stQ, oo);
  const unsigned short* qp16 = q16 + lb;
  #pragma unroll
  for (int mt = 0; mt < 6; ++mt)
    qacc[mt] = __builtin_amdgcn_mfma_f32_16x16x32_bf16(pre[mt], mxb[0], qacc[mt], 0, 0, 0);
  load6s(pre, k16 + lb, 3);
  #pragma unroll
  for (int kt = 1; kt < 3; ++kt)
    #pragma unroll
    for (int mt = 0; mt < 6; ++mt) {
      const bh8 af = *reinterpret_cast<const bh8*>(qp16 + ((mt * 3 + kt) << 9));
      qacc[mt] = __builtin_amdgcn_mfma_f32_16x16x32_bf16(af, mxb[kt], qacc[mt], 0, 0, 0);
    }
  // ---- K: kt0 from pre; refill pre <- V g0 ----
  f4 kacc[6];
  init6(kacc, stQ + 96, oo);
  const unsigned short* kp16 = k16 + lb;
  #pragma unroll
  for (int mt = 0; mt < 6; ++mt)
    kacc[mt] = __builtin_amdgcn_mfma_f32_16x16x32_bf16(pre[mt], gfr[0], kacc[mt], 0, 0, 0);
  load6s(pre, v16 + lb, 3);
  #pragma unroll
  for (int kt = 1; kt < 3; ++kt)
    #pragma unroll
    for (int mt = 0; mt < 6; ++mt) {
      const bh8 af = *reinterpret_cast<const bh8*>(kp16 + ((mt * 3 + kt) << 9));
      kacc[mt] = __builtin_amdgcn_mfma_f32_16x16x32_bf16(af, gfr[kt], kacc[mt], 0, 0, 0);
    }
  float p0 = 0.f, p1 = 0.f;
  #pragma unroll
  for (int mt = 0; mt < 6; ++mt) {
    p0 = fmaf(qacc[mt][0], kacc[mt][0], p0);
    p1 = fmaf(qacc[mt][1], kacc[mt][1], p1);
    p0 = fmaf(qacc[mt][2], kacc[mt][2], p0);
    p1 = fmaf(qacc[mt][3], kacc[mt][3], p1);
  }
  float p = p0 + p1;
  p += __shfl_xor(p, 16); p += __shfl_xor(p, 32);
  const float sig = 1.f / (1.f + __expf(-p * 0.10206207261596575f));

  // ---- V: kt0 from pre; refill pre <- O g0 ----
  f4 vacc[6];
  init6(vacc, stQ + 192, oo);
  const unsigned short* vp16 = v16 + lb;
  #pragma unroll
  for (int mt = 0; mt < 6; ++mt)
    vacc[mt] = __builtin_amdgcn_mfma_f32_16x16x32_bf16(pre[mt], gfr[0], vacc[mt], 0, 0, 0);
  load6s(pre, o16 + lb, 3);
  #pragma unroll
  for (int kt = 1; kt < 3; ++kt)
    #pragma unroll
    for (int mt = 0; mt < 6; ++mt) {
      const bh8 af = *reinterpret_cast<const bh8*>(vp16 + ((mt * 3 + kt) << 9));
      vacc[mt] = __builtin_amdgcn_mfma_f32_16x16x32_bf16(af, gfr[kt], vacc[mt], 0, 0, 0);
    }
  #pragma unroll
  for (int mt = 0; mt < 6; ++mt) {
    uint2 u;
    u.x = pk2(vacc[mt][0] * sig, vacc[mt][1] * sig);
    u.y = pk2(vacc[mt][2] * sig, vacc[mt][3] * sig);
    *reinterpret_cast<uint2*>(xw + ((mt * 16 + g * 4) ^ sw)) = u;
  }
  // residual loads issue before the wait
  float mres[6][4];
  #pragma unroll
  for (int mt = 0; mt < 6; ++mt)
    #pragma unroll
    for (int r = 0; r < 4; ++r) mres[mt][r] = mxL[(mt * 16 + g * 4 + r) * FT];
  LDSWAIT;
  bh8 afr[3];
  #pragma unroll
  for (int kt = 0; kt < 3; ++kt) afr[kt] = *reinterpret_cast<const bh8*>(xw + ((kt * 32 + g * 8) ^ sw));

  // ---- O: kt0 from pre ----
  f4 oacc[6];
  init6(oacc, stQ + 288, oo);
  const unsigned short* op16 = o16 + lb;
  #pragma unroll
  for (int mt = 0; mt < 6; ++mt)
    oacc[mt] = __builtin_amdgcn_mfma_f32_16x16x32_bf16(pre[mt], afr[0], oacc[mt], 0, 0, 0);
  #pragma unroll
  for (int kt = 1; kt < 3; ++kt)
    #pragma unroll
    for (int mt = 0; mt < 6; ++mt) {
      const bh8 af = *reinterpret_cast<const bh8*>(op16 + ((mt * 3 + kt) << 9));
      oacc[mt] = __builtin_amdgcn_mfma_f32_16x16x32_bf16(af, afr[kt], oacc[mt], 0, 0, 0);
    }

  __syncthreads();   // ALL waves done with XT/stage before aliased OS writes

  #pragma unroll
  for (int mt = 0; mt < 6; ++mt)
    #pragma unroll
    for (int r = 0; r < 4; ++r)
      OS[(mt * 16 + g * 4 + r) * 65 + col] = mres[mt][r] + oacc[mt][r];

  __syncthreads();   // all waves' OS writes visible

  // ---- block-coalesced full-line NT stores ----
  const int cvalid = 1000 - t0;   // valid columns in this tile
  #pragma unroll
  for (int it = 0; it < 24; ++it) {
    const int i   = it * 256 + tid;
    const int row = i >> 6;
    const int c   = i & 63;
    const float val = OS[row * 65 + c];
    if (c < cvalid)
      __builtin_nontemporal_store(val, out + (b * 96 + row) * FT + f * 1000 + t0 + c);
  }
}

extern "C" void kernel_launch(void* const* d_in, const int* in_sizes, int n_in,
                              void* d_out, int out_size, void* d_ws, size_t ws_size,
                              hipStream_t stream) {
  (void)in_sizes; (void)n_in; (void)out_size; (void)ws_size;
  const float* mix   = (const float*)d_in[0];
  const float* spin  = (const float*)d_in[1];
  const float* doa   = (const float*)d_in[2];
  const float* enc_w = (const float*)d_in[3];
  const float* enc_b = (const float*)d_in[4];
  const float* enc_a = (const float*)d_in[5];
  const float* dqg_w = (const float*)d_in[6];
  const float* dqg_b = (const float*)d_in[7];
  const float* dec_w = (const float*)d_in[8];
  const float* dec_b = (const float*)d_in[9];
  const float* dec_a = (const float*)d_in[10];
  const float* qw    = (const float*)d_in[11];
  const float* qb    = (const float*)d_in[12];
  const float* kw    = (const float*)d_in[13];
  const float* kb    = (const float*)d_in[14];
  const float* vw    = (const float*)d_in[15];
  const float* vb    = (const float*)d_in[16];
  const float* oww   = (const float*)d_in[17];
  const float* obb   = (const float*)d_in[18];
  float* outp = (float*)d_out;

  unsigned short* w16 = (unsigned short*)d_ws;
  unsigned short* enc16 = w16;                 // 31*6144
  unsigned short* dec16 = w16 + 190464;        // 31*9216
  unsigned short* q16   = w16 + 476160;
  unsigned short* k16   = q16 + 9216;
  unsigned short* v16   = k16 + 9216;
  unsigned short* o16   = v16 + 9216;
  float* gbws = (float*)((char*)d_ws + 1026048);  // 31*4*192 f32 (95232 B)
  float* ftab = (float*)((char*)d_ws + 1121280);  // 257*8 f32 (8224 B)

  hipLaunchKernelGGL(prep_w, dim3(512), dim3(256), 0, stream,
                     enc_w, dec_w, qw, kw, vw, oww, w16);
  hipLaunchKernelGGL(qp_kernel, dim3(NBANDS, 4), dim3(192), 0, stream,
                     doa, dqg_w, dqg_b, gbws);
  hipLaunchKernelGGL(tab_kernel, dim3(1), dim3(320), 0, stream, ftab);
  hipLaunchKernelGGL(fused_mfma, dim3(16448), dim3(256), 0, stream,
                     mix, spin, enc16, enc_b, enc_a, dec16, dec_b, dec_a, gbws, ftab,
                     q16, qb, k16, kb, v16, vb, o16, obb, outp);
}